// Round 5
// baseline (483.250 us; speedup 1.0000x reference)
//
#include <hip/hip_runtime.h>
#include <hip/hip_bf16.h>

typedef __attribute__((ext_vector_type(8))) short short8;
typedef __attribute__((ext_vector_type(4))) float f32x4;

#define NROWS 8192

__device__ inline short f2bf(float f) {
  union { float f; unsigned u; } v; v.f = f;
  unsigned r = v.u + 0x7FFFu + ((v.u >> 16) & 1u);
  return (short)(r >> 16);
}

// fc1_W [K][64] fp32 -> WT [64][K] bf16 (transposed)
__global__ __launch_bounds__(256) void convert_w_kernel(
    const float* __restrict__ W, short* __restrict__ WT, int K, int N) {
  int gid = blockIdx.x * 256 + threadIdx.x;
  if (gid >= K * N) return;
  int n = gid / K, k = gid - n * K;
  WT[gid] = f2bf(W[(size_t)k * N + n]);
}

// tT[n][m] = sum_j H[m][j] * W[j][n]  (rows n >= Nout written as zero)
__global__ __launch_bounds__(256) void small_t_kernel(
    const float* __restrict__ H, const float* __restrict__ W,
    short* __restrict__ tT, int Nout, int ldw) {
  __shared__ float Ws[64][64];
  int tid = threadIdx.x;
  for (int i = tid; i < 64 * 64; i += 256) {
    int j = i >> 6, n = i & 63;
    Ws[j][n] = (n < Nout) ? W[j * ldw + n] : 0.0f;
  }
  __syncthreads();
  int gid = blockIdx.x * 256 + tid;
  int m = gid >> 2;            // 4 threads per row
  int nq = (gid & 3) << 4;     // 16 columns each
  const float* hrow = H + (size_t)m * 64;
  float hr[64];
#pragma unroll
  for (int j = 0; j < 64; j += 4) {
    f32x4 v = *(const f32x4*)(hrow + j);
    hr[j] = v.x; hr[j + 1] = v.y; hr[j + 2] = v.z; hr[j + 3] = v.w;
  }
#pragma unroll
  for (int ni = 0; ni < 16; ++ni) {
    int n = nq + ni;
    float acc = 0.0f;
#pragma unroll
    for (int j = 0; j < 64; ++j) acc += hr[j] * Ws[j][n];
    tT[(size_t)n * NROWS + m] = f2bf(acc);
  }
}

// P[y][8192][64] = A(fp32, cvt in-loop, nontemporal) @ BT^T ; optional bf16 A store.
// Unroll-2 batched loads (k-step 64). grid = (M/64, splitk).
__global__ __launch_bounds__(256) void gemm_a32_u2(
    const float* __restrict__ A, const short* __restrict__ BT,
    float* __restrict__ P, short* __restrict__ AB, int K, int splitk) {
  int w = threadIdx.x >> 6;
  int l = threadIdx.x & 63;
  int l15 = l & 15, kg = l >> 4;
  int m_base = blockIdx.x * 64 + w * 16;
  int row = m_base + l15;
  const float* Arow = A + (size_t)row * K;
  const short* Br = BT + (size_t)l15 * K;
  int kchunk = K / splitk;
  int k0 = blockIdx.y * kchunk;
  f32x4 acc[4] = {{0,0,0,0},{0,0,0,0},{0,0,0,0},{0,0,0,0}};
  for (int k = k0; k < k0 + kchunk; k += 64) {
    f32x4 a32[2][2];
    short8 b[2][4];
#pragma unroll
    for (int u = 0; u < 2; ++u) {
      int kk = k + u * 32 + kg * 8;
      a32[u][0] = __builtin_nontemporal_load((const f32x4*)(Arow + kk));
      a32[u][1] = __builtin_nontemporal_load((const f32x4*)(Arow + kk + 4));
      b[u][0] = *(const short8*)(Br + kk);
      b[u][1] = *(const short8*)(Br + (size_t)16 * K + kk);
      b[u][2] = *(const short8*)(Br + (size_t)32 * K + kk);
      b[u][3] = *(const short8*)(Br + (size_t)48 * K + kk);
    }
#pragma unroll
    for (int u = 0; u < 2; ++u) {
      int kk = k + u * 32 + kg * 8;
      short8 af;
      af[0] = f2bf(a32[u][0].x); af[1] = f2bf(a32[u][0].y);
      af[2] = f2bf(a32[u][0].z); af[3] = f2bf(a32[u][0].w);
      af[4] = f2bf(a32[u][1].x); af[5] = f2bf(a32[u][1].y);
      af[6] = f2bf(a32[u][1].z); af[7] = f2bf(a32[u][1].w);
      if (AB) *(short8*)(AB + (size_t)row * K + kk) = af;
#pragma unroll
      for (int t = 0; t < 4; ++t)
        acc[t] = __builtin_amdgcn_mfma_f32_16x16x32_bf16(af, b[u][t], acc[t], 0, 0, 0);
    }
  }
  float* Pb = P + (size_t)blockIdx.y * (NROWS * 64);
  int mr = m_base + kg * 4;
#pragma unroll
  for (int r = 0; r < 4; ++r) {
    size_t base = (size_t)(mr + r) * 64 + l15;
#pragma unroll
    for (int t = 0; t < 4; ++t) Pb[base + 16 * t] = acc[t][r];
  }
}

// P[y][8192][64] = AB(bf16) @ BT^T. Unroll-4 batched loads (k-step 128).
__global__ __launch_bounds__(256) void gemm_bf16_u4(
    const short* __restrict__ AB, const short* __restrict__ BT,
    float* __restrict__ P, int K, int splitk) {
  int w = threadIdx.x >> 6;
  int l = threadIdx.x & 63;
  int l15 = l & 15, kg = l >> 4;
  int m_base = blockIdx.x * 64 + w * 16;
  const short* Arow = AB + (size_t)(m_base + l15) * K;
  const short* Br = BT + (size_t)l15 * K;
  int kchunk = K / splitk;
  int k0 = blockIdx.y * kchunk;
  f32x4 acc[4] = {{0,0,0,0},{0,0,0,0},{0,0,0,0},{0,0,0,0}};
  for (int k = k0; k < k0 + kchunk; k += 128) {
    short8 a[4], b[4][4];
#pragma unroll
    for (int u = 0; u < 4; ++u) {
      int kk = k + u * 32 + kg * 8;
      a[u]    = *(const short8*)(Arow + kk);
      b[u][0] = *(const short8*)(Br + kk);
      b[u][1] = *(const short8*)(Br + (size_t)16 * K + kk);
      b[u][2] = *(const short8*)(Br + (size_t)32 * K + kk);
      b[u][3] = *(const short8*)(Br + (size_t)48 * K + kk);
    }
#pragma unroll
    for (int u = 0; u < 4; ++u)
#pragma unroll
      for (int t = 0; t < 4; ++t)
        acc[t] = __builtin_amdgcn_mfma_f32_16x16x32_bf16(a[u], b[u][t], acc[t], 0, 0, 0);
  }
  float* Pb = P + (size_t)blockIdx.y * (NROWS * 64);
  int mr = m_base + kg * 4;
#pragma unroll
  for (int r = 0; r < 4; ++r) {
    size_t base = (size_t)(mr + r) * 64 + l15;
#pragma unroll
    for (int t = 0; t < 4; ++t) Pb[base + 16 * t] = acc[t][r];
  }
}

// sum split-K partials + bias (+ residual, relu); float4 per thread.
__global__ __launch_bounds__(256) void reduce4_kernel(
    const float* __restrict__ P, const float* __restrict__ bias,
    const float* __restrict__ Hres, float* __restrict__ Hout,
    float* __restrict__ Out, int mode, int splitk) {
  int gid = blockIdx.x * 256 + threadIdx.x;   // over 8192*16 groups of 4
  int e0 = gid * 4;
  int n = e0 & 63;
  f32x4 s = {0, 0, 0, 0};
  for (int sidx = 0; sidx < splitk; ++sidx) {
    f32x4 p = *(const f32x4*)(P + (size_t)sidx * (NROWS * 64) + e0);
    s += p;
  }
  f32x4 bb = *(const f32x4*)(bias + n);
  s += bb;
  if (mode == 0) {
    *(f32x4*)(Hout + e0) = s;
  } else if (mode == 1) {
    f32x4 r = *(const f32x4*)(Hres + e0);
    s += r;
    s.x = s.x > 0.f ? s.x : 0.f; s.y = s.y > 0.f ? s.y : 0.f;
    s.z = s.z > 0.f ? s.z : 0.f; s.w = s.w > 0.f ? s.w : 0.f;
    *(f32x4*)(Hout + e0) = s;
  } else {
    if (n < 40) {
      int m = e0 >> 6;
      s.x = s.x > 0.f ? s.x : 0.f; s.y = s.y > 0.f ? s.y : 0.f;
      s.z = s.z > 0.f ? s.z : 0.f; s.w = s.w > 0.f ? s.w : 0.f;
      *(f32x4*)(Out + (size_t)m * 40 + n) = s;
    }
  }
}

extern "C" void kernel_launch(void* const* d_in, const int* in_sizes, int n_in,
                              void* d_out, int out_size, void* d_ws, size_t ws_size,
                              hipStream_t stream) {
  const float* x     = (const float*)d_in[0];
  const float* adj1  = (const float*)d_in[1];
  const float* fc1_W = (const float*)d_in[3];
  const float* fc1_b = (const float*)d_in[4];
  const float* W_h   = (const float*)d_in[5];
  const float* b_h   = (const float*)d_in[6];
  const float* W_out = (const float*)d_in[7];
  const float* b_out = (const float*)d_in[8];
  float* out = (float*)d_out;

  const int SK = 8;   // split-K: 1024 blocks, 4 blocks/CU, 16 waves/CU

  char* ws = (char*)d_ws;
  size_t off = 0;
  float* P   = (float*)(ws + off); off += (size_t)SK * NROWS * 64 * 4;   // 16 MiB
  float* h_a = (float*)(ws + off); off += (size_t)NROWS * 64 * 4;
  float* h_b = (float*)(ws + off); off += (size_t)NROWS * 64 * 4;
  short* tT  = (short*)(ws + off); off += (size_t)64 * NROWS * 2;
  short* WT  = (short*)(ws + off); off += (size_t)64 * 1024 * 2;
  size_t adjb_bytes = (size_t)NROWS * NROWS * 2;                         // 128 MiB
  short* AB  = (ws_size - off >= adjb_bytes) ? (short*)(ws + off) : nullptr;

  const int RED_GRID = NROWS * 64 / 4 / 256;

  // fc1: h = x @ fc1_W + b
  convert_w_kernel<<<(1024 * 64 + 255) / 256, 256, 0, stream>>>(fc1_W, WT, 1024, 64);
  gemm_a32_u2<<<dim3(NROWS / 64, SK), 256, 0, stream>>>(x, WT, P, nullptr, 1024, SK);
  reduce4_kernel<<<RED_GRID, 256, 0, stream>>>(P, fc1_b, nullptr, h_a, nullptr, 0, SK);

  float* hc = h_a; float* hn = h_b;
  for (int i = 0; i < 3; ++i) {
    small_t_kernel<<<NROWS * 4 / 256, 256, 0, stream>>>(hc, W_h + (size_t)i * 64 * 64, tT, 64, 64);
    if (i == 0)  // first adj pass: compute + convert adj1 -> bf16 AB
      gemm_a32_u2<<<dim3(NROWS / 64, SK), 256, 0, stream>>>(adj1, tT, P, AB, NROWS, SK);
    else if (AB)
      gemm_bf16_u4<<<dim3(NROWS / 64, SK), 256, 0, stream>>>(AB, tT, P, NROWS, SK);
    else
      gemm_a32_u2<<<dim3(NROWS / 64, SK), 256, 0, stream>>>(adj1, tT, P, nullptr, NROWS, SK);
    reduce4_kernel<<<RED_GRID, 256, 0, stream>>>(P, b_h + (size_t)i * 64, hc, hn, nullptr, 1, SK);
    float* t = hc; hc = hn; hn = t;
  }

  small_t_kernel<<<NROWS * 4 / 256, 256, 0, stream>>>(hc, W_out, tT, 40, 40);
  if (AB)
    gemm_bf16_u4<<<dim3(NROWS / 64, SK), 256, 0, stream>>>(AB, tT, P, NROWS, SK);
  else
    gemm_a32_u2<<<dim3(NROWS / 64, SK), 256, 0, stream>>>(adj1, tT, P, nullptr, NROWS, SK);
  reduce4_kernel<<<RED_GRID, 256, 0, stream>>>(P, b_out, nullptr, nullptr, out, 2, SK);
}

// Round 6
// 310.814 us; speedup vs baseline: 1.5548x; 1.5548x over previous
//
#include <hip/hip_runtime.h>
#include <hip/hip_bf16.h>

typedef __attribute__((ext_vector_type(8))) short short8;
typedef __attribute__((ext_vector_type(4))) float f32x4;

#define NROWS 8192
#define BK 512        // LDS B-stage width (k)
#define NSTAGE 4      // stages per block -> k-chunk 2048
#define SK 4          // split-K slices (and P slices)

__device__ inline short f2bf(float f) {
  union { float f; unsigned u; } v; v.f = f;
  unsigned r = v.u + 0x7FFFu + ((v.u >> 16) & 1u);
  return (short)(r >> 16);
}

// adj1 fp32 [8192][8192] -> AB bf16, pure streaming
__global__ __launch_bounds__(256) void convert_adj_kernel(
    const float* __restrict__ A, short* __restrict__ AB) {
  const size_t total = (size_t)NROWS * NROWS;
  size_t i0 = ((size_t)blockIdx.x * 256 + threadIdx.x) * 8;
  size_t stride = (size_t)gridDim.x * 256 * 8;
  for (size_t i = i0; i < total; i += stride) {
    f32x4 a = __builtin_nontemporal_load((const f32x4*)(A + i));
    f32x4 b = __builtin_nontemporal_load((const f32x4*)(A + i + 4));
    short8 o;
    o[0] = f2bf(a.x); o[1] = f2bf(a.y); o[2] = f2bf(a.z); o[3] = f2bf(a.w);
    o[4] = f2bf(b.x); o[5] = f2bf(b.y); o[6] = f2bf(b.z); o[7] = f2bf(b.w);
    *(short8*)(AB + i) = o;
  }
}

// fc1_W [K][64] fp32 -> WT [64][K] bf16 (transposed)
__global__ __launch_bounds__(256) void convert_w_kernel(
    const float* __restrict__ W, short* __restrict__ WT, int K, int N) {
  int gid = blockIdx.x * 256 + threadIdx.x;
  if (gid >= K * N) return;
  int n = gid / K, k = gid - n * K;
  WT[gid] = f2bf(W[(size_t)k * N + n]);
}

// tT[n][m] = sum_j H[m][j] * W[j][n]  (rows n >= Nout written as zero)
__global__ __launch_bounds__(256) void small_t_kernel(
    const float* __restrict__ H, const float* __restrict__ W,
    short* __restrict__ tT, int Nout, int ldw) {
  __shared__ float Ws[64][64];
  int tid = threadIdx.x;
  for (int i = tid; i < 64 * 64; i += 256) {
    int j = i >> 6, n = i & 63;
    Ws[j][n] = (n < Nout) ? W[j * ldw + n] : 0.0f;
  }
  __syncthreads();
  int gid = blockIdx.x * 256 + tid;
  int m = gid >> 2;            // 4 threads per row
  int nq = (gid & 3) << 4;     // 16 columns each
  const float* hrow = H + (size_t)m * 64;
  float hr[64];
#pragma unroll
  for (int j = 0; j < 64; j += 4) {
    f32x4 v = *(const f32x4*)(hrow + j);
    hr[j] = v.x; hr[j + 1] = v.y; hr[j + 2] = v.z; hr[j + 3] = v.w;
  }
#pragma unroll
  for (int ni = 0; ni < 16; ++ni) {
    int n = nq + ni;
    float acc = 0.0f;
#pragma unroll
    for (int j = 0; j < 64; ++j) acc += hr[j] * Ws[j][n];
    tT[(size_t)n * NROWS + m] = f2bf(acc);
  }
}

// P[y][8192][64] = AB(bf16)[8192][8192] @ BT^T, B staged in LDS.
// grid = (128, SK). Each block: NSTAGE sequential B-stages of BK.
__global__ __launch_bounds__(256, 2) void gemm_bf16_lds(
    const short* __restrict__ AB, const short* __restrict__ BT,
    float* __restrict__ P) {
  __shared__ short Bs[64][BK + 8];   // +8 shorts pad: row stride 1040B -> 2-way (free)
  int tid = threadIdx.x;
  int w = tid >> 6, l = tid & 63;
  int l15 = l & 15, kg = l >> 4;
  int m_base = blockIdx.x * 64 + w * 16;
  const short* Arow = AB + (size_t)(m_base + l15) * NROWS;
  int k0 = blockIdx.y * (NROWS / SK);
  f32x4 acc[4] = {{0,0,0,0},{0,0,0,0},{0,0,0,0},{0,0,0,0}};
  for (int stage = 0; stage < NSTAGE; ++stage) {
    int ks = k0 + stage * BK;
    for (int i = tid; i < 64 * (BK / 8); i += 256) {   // 16 iters: 64KB B-chunk
      int r = i >> 6;
      int c = (i & 63) << 3;
      *(short8*)&Bs[r][c] = *(const short8*)(BT + (size_t)r * NROWS + ks + c);
    }
    __syncthreads();
#pragma unroll
    for (int k = 0; k < BK; k += 128) {
      short8 a[4], b[4][4];
#pragma unroll
      for (int u = 0; u < 4; ++u) {
        int kk = k + u * 32 + kg * 8;
        a[u] = *(const short8*)(Arow + ks + kk);
      }
#pragma unroll
      for (int u = 0; u < 4; ++u) {
        int kk = k + u * 32 + kg * 8;
        b[u][0] = *(const short8*)&Bs[l15 +  0][kk];
        b[u][1] = *(const short8*)&Bs[l15 + 16][kk];
        b[u][2] = *(const short8*)&Bs[l15 + 32][kk];
        b[u][3] = *(const short8*)&Bs[l15 + 48][kk];
      }
#pragma unroll
      for (int u = 0; u < 4; ++u)
#pragma unroll
        for (int t = 0; t < 4; ++t)
          acc[t] = __builtin_amdgcn_mfma_f32_16x16x32_bf16(a[u], b[u][t], acc[t], 0, 0, 0);
    }
    __syncthreads();
  }
  float* Pb = P + (size_t)blockIdx.y * (NROWS * 64);
  int mr = m_base + kg * 4;
#pragma unroll
  for (int r = 0; r < 4; ++r) {
    size_t base = (size_t)(mr + r) * 64 + l15;
#pragma unroll
    for (int t = 0; t < 4; ++t) Pb[base + 16 * t] = acc[t][r];
  }
}

// P[y][8192][64] = A(fp32, cvt in-loop) @ BT^T (fc1 only). grid (128, SK).
__global__ __launch_bounds__(256, 2) void gemm_a32_u2(
    const float* __restrict__ A, const short* __restrict__ BT,
    float* __restrict__ P, int K, int splitk) {
  int w = threadIdx.x >> 6;
  int l = threadIdx.x & 63;
  int l15 = l & 15, kg = l >> 4;
  int m_base = blockIdx.x * 64 + w * 16;
  const float* Arow = A + (size_t)(m_base + l15) * K;
  const short* Br = BT + (size_t)l15 * K;
  int kchunk = K / splitk;
  int k0 = blockIdx.y * kchunk;
  f32x4 acc[4] = {{0,0,0,0},{0,0,0,0},{0,0,0,0},{0,0,0,0}};
  for (int k = k0; k < k0 + kchunk; k += 64) {
    f32x4 a32[2][2];
    short8 b[2][4];
#pragma unroll
    for (int u = 0; u < 2; ++u) {
      int kk = k + u * 32 + kg * 8;
      a32[u][0] = __builtin_nontemporal_load((const f32x4*)(Arow + kk));
      a32[u][1] = __builtin_nontemporal_load((const f32x4*)(Arow + kk + 4));
      b[u][0] = *(const short8*)(Br + kk);
      b[u][1] = *(const short8*)(Br + (size_t)16 * K + kk);
      b[u][2] = *(const short8*)(Br + (size_t)32 * K + kk);
      b[u][3] = *(const short8*)(Br + (size_t)48 * K + kk);
    }
#pragma unroll
    for (int u = 0; u < 2; ++u) {
      short8 af;
      af[0] = f2bf(a32[u][0].x); af[1] = f2bf(a32[u][0].y);
      af[2] = f2bf(a32[u][0].z); af[3] = f2bf(a32[u][0].w);
      af[4] = f2bf(a32[u][1].x); af[5] = f2bf(a32[u][1].y);
      af[6] = f2bf(a32[u][1].z); af[7] = f2bf(a32[u][1].w);
#pragma unroll
      for (int t = 0; t < 4; ++t)
        acc[t] = __builtin_amdgcn_mfma_f32_16x16x32_bf16(af, b[u][t], acc[t], 0, 0, 0);
    }
  }
  float* Pb = P + (size_t)blockIdx.y * (NROWS * 64);
  int mr = m_base + kg * 4;
#pragma unroll
  for (int r = 0; r < 4; ++r) {
    size_t base = (size_t)(mr + r) * 64 + l15;
#pragma unroll
    for (int t = 0; t < 4; ++t) Pb[base + 16 * t] = acc[t][r];
  }
}

// sum split-K partials + bias (+ residual, relu); float4 per thread.
__global__ __launch_bounds__(256) void reduce4_kernel(
    const float* __restrict__ P, const float* __restrict__ bias,
    const float* __restrict__ Hres, float* __restrict__ Hout,
    float* __restrict__ Out, int mode, int splitk) {
  int gid = blockIdx.x * 256 + threadIdx.x;   // over 8192*16 groups of 4
  int e0 = gid * 4;
  int n = e0 & 63;
  f32x4 s = {0, 0, 0, 0};
  for (int sidx = 0; sidx < splitk; ++sidx)
    s += *(const f32x4*)(P + (size_t)sidx * (NROWS * 64) + e0);
  s += *(const f32x4*)(bias + n);
  if (mode == 0) {
    *(f32x4*)(Hout + e0) = s;
  } else if (mode == 1) {
    s += *(const f32x4*)(Hres + e0);
    s.x = s.x > 0.f ? s.x : 0.f; s.y = s.y > 0.f ? s.y : 0.f;
    s.z = s.z > 0.f ? s.z : 0.f; s.w = s.w > 0.f ? s.w : 0.f;
    *(f32x4*)(Hout + e0) = s;
  } else {
    if (n < 40) {
      int m = e0 >> 6;
      s.x = s.x > 0.f ? s.x : 0.f; s.y = s.y > 0.f ? s.y : 0.f;
      s.z = s.z > 0.f ? s.z : 0.f; s.w = s.w > 0.f ? s.w : 0.f;
      *(f32x4*)(Out + (size_t)m * 40 + n) = s;
    }
  }
}

extern "C" void kernel_launch(void* const* d_in, const int* in_sizes, int n_in,
                              void* d_out, int out_size, void* d_ws, size_t ws_size,
                              hipStream_t stream) {
  const float* x     = (const float*)d_in[0];
  const float* adj1  = (const float*)d_in[1];
  const float* fc1_W = (const float*)d_in[3];
  const float* fc1_b = (const float*)d_in[4];
  const float* W_h   = (const float*)d_in[5];
  const float* b_h   = (const float*)d_in[6];
  const float* W_out = (const float*)d_in[7];
  const float* b_out = (const float*)d_in[8];
  float* out = (float*)d_out;

  char* ws = (char*)d_ws;
  size_t off = 0;
  float* P   = (float*)(ws + off); off += (size_t)SK * NROWS * 64 * 4;   // 8 MiB
  float* h_a = (float*)(ws + off); off += (size_t)NROWS * 64 * 4;
  float* h_b = (float*)(ws + off); off += (size_t)NROWS * 64 * 4;
  short* tT  = (short*)(ws + off); off += (size_t)64 * NROWS * 2;
  short* WT  = (short*)(ws + off); off += (size_t)64 * 1024 * 2;
  size_t adjb_bytes = (size_t)NROWS * NROWS * 2;                         // 128 MiB
  short* AB  = (ws_size - off >= adjb_bytes) ? (short*)(ws + off) : nullptr;

  const int RED_GRID = NROWS * 64 / 4 / 256;

  if (AB)
    convert_adj_kernel<<<2048, 256, 0, stream>>>(adj1, AB);

  // fc1: h = x @ fc1_W + b
  convert_w_kernel<<<(1024 * 64 + 255) / 256, 256, 0, stream>>>(fc1_W, WT, 1024, 64);
  gemm_a32_u2<<<dim3(NROWS / 64, SK), 256, 0, stream>>>(x, WT, P, 1024, SK);
  reduce4_kernel<<<RED_GRID, 256, 0, stream>>>(P, fc1_b, nullptr, h_a, nullptr, 0, SK);

  float* hc = h_a; float* hn = h_b;
  for (int i = 0; i < 3; ++i) {
    small_t_kernel<<<NROWS * 4 / 256, 256, 0, stream>>>(hc, W_h + (size_t)i * 64 * 64, tT, 64, 64);
    if (AB)
      gemm_bf16_lds<<<dim3(NROWS / 64, SK), 256, 0, stream>>>(AB, tT, P);
    else
      gemm_a32_u2<<<dim3(NROWS / 64, SK), 256, 0, stream>>>(adj1, tT, P, NROWS, SK);
    reduce4_kernel<<<RED_GRID, 256, 0, stream>>>(P, b_h + (size_t)i * 64, hc, hn, nullptr, 1, SK);
    float* t = hc; hc = hn; hn = t;
  }

  small_t_kernel<<<NROWS * 4 / 256, 256, 0, stream>>>(hc, W_out, tT, 40, 40);
  if (AB)
    gemm_bf16_lds<<<dim3(NROWS / 64, SK), 256, 0, stream>>>(AB, tT, P);
  else
    gemm_a32_u2<<<dim3(NROWS / 64, SK), 256, 0, stream>>>(adj1, tT, P, NROWS, SK);
  reduce4_kernel<<<RED_GRID, 256, 0, stream>>>(P, b_out, nullptr, nullptr, out, 2, SK);
}

// Round 7
// 252.907 us; speedup vs baseline: 1.9108x; 1.2290x over previous
//
#include <hip/hip_runtime.h>
#include <hip/hip_bf16.h>

typedef __attribute__((ext_vector_type(8))) short short8;
typedef __attribute__((ext_vector_type(4))) float f32x4;

#define NROWS 8192
#define BK 256        // LDS B-stage width (k)
#define MTILE 128     // rows per block (4 waves x 32 rows)
#define SK 8          // split-K slices

__device__ inline short f2bf(float f) {
  union { float f; unsigned u; } v; v.f = f;
  unsigned r = v.u + 0x7FFFu + ((v.u >> 16) & 1u);
  return (short)(r >> 16);
}

// adj1 fp32 [8192][8192] -> AB bf16, pure streaming
__global__ __launch_bounds__(256) void convert_adj_kernel(
    const float* __restrict__ A, short* __restrict__ AB) {
  const size_t total = (size_t)NROWS * NROWS;
  size_t i0 = ((size_t)blockIdx.x * 256 + threadIdx.x) * 8;
  size_t stride = (size_t)gridDim.x * 256 * 8;
  for (size_t i = i0; i < total; i += stride) {
    f32x4 a = __builtin_nontemporal_load((const f32x4*)(A + i));
    f32x4 b = __builtin_nontemporal_load((const f32x4*)(A + i + 4));
    short8 o;
    o[0] = f2bf(a.x); o[1] = f2bf(a.y); o[2] = f2bf(a.z); o[3] = f2bf(a.w);
    o[4] = f2bf(b.x); o[5] = f2bf(b.y); o[6] = f2bf(b.z); o[7] = f2bf(b.w);
    *(short8*)(AB + i) = o;
  }
}

// fc1_W [K][64] fp32 -> WT [64][K] bf16 (transposed)
__global__ __launch_bounds__(256) void convert_w_kernel(
    const float* __restrict__ W, short* __restrict__ WT, int K, int N) {
  int gid = blockIdx.x * 256 + threadIdx.x;
  if (gid >= K * N) return;
  int n = gid / K, k = gid - n * K;
  WT[gid] = f2bf(W[(size_t)k * N + n]);
}

// tT[n][m] = sum_j H[m][j] * W[j][n]  (rows n >= Nout written as zero)
__global__ __launch_bounds__(256) void small_t_kernel(
    const float* __restrict__ H, const float* __restrict__ W,
    short* __restrict__ tT, int Nout, int ldw) {
  __shared__ float Ws[64][64];
  int tid = threadIdx.x;
  for (int i = tid; i < 64 * 64; i += 256) {
    int j = i >> 6, n = i & 63;
    Ws[j][n] = (n < Nout) ? W[j * ldw + n] : 0.0f;
  }
  __syncthreads();
  int gid = blockIdx.x * 256 + tid;
  int m = gid >> 2;            // 4 threads per row
  int nq = (gid & 3) << 4;     // 16 columns each
  const float* hrow = H + (size_t)m * 64;
  float hr[64];
#pragma unroll
  for (int j = 0; j < 64; j += 4) {
    f32x4 v = *(const f32x4*)(hrow + j);
    hr[j] = v.x; hr[j + 1] = v.y; hr[j + 2] = v.z; hr[j + 3] = v.w;
  }
#pragma unroll
  for (int ni = 0; ni < 16; ++ni) {
    int n = nq + ni;
    float acc = 0.0f;
#pragma unroll
    for (int j = 0; j < 64; ++j) acc += hr[j] * Ws[j][n];
    tT[(size_t)n * NROWS + m] = f2bf(acc);
  }
}

// P[y][8192][64] = AB(bf16)[8192][8192] @ BT^T.
// Block: 128 rows x 64 cols, wave: 32 rows x 64 cols (8 MFMA tiles).
// B double-buffered in LDS (reg-staged); A streamed from global.
// grid = (64, SK).
__global__ __launch_bounds__(256, 2) void gemm_bf16_lds2(
    const short* __restrict__ AB, const short* __restrict__ BT,
    float* __restrict__ P) {
  __shared__ short Bs[2][64][BK + 8];   // 67.6 KB -> 2 blocks/CU
  int tid = threadIdx.x;
  int w = tid >> 6, l = tid & 63;
  int l15 = l & 15, kg = l >> 4;
  int m_base = blockIdx.x * MTILE;
  int wrow = m_base + w * 32;
  const short* A0 = AB + (size_t)(wrow + l15) * NROWS;
  const short* A1 = AB + (size_t)(wrow + 16 + l15) * NROWS;
  const int KCH = NROWS / SK;           // 1024
  const int NST = KCH / BK;             // 4 stages
  int k0 = blockIdx.y * KCH;
  f32x4 acc[2][4];
#pragma unroll
  for (int rt = 0; rt < 2; ++rt)
#pragma unroll
    for (int ct = 0; ct < 4; ++ct) acc[rt][ct] = (f32x4){0, 0, 0, 0};

  short8 st[8];
  // prologue: stage 0 -> regs -> LDS buf0
#pragma unroll
  for (int j = 0; j < 8; ++j) {
    int slot = tid + 256 * j;
    int r = slot >> 5, c = (slot & 31) << 3;
    st[j] = *(const short8*)(BT + (size_t)r * NROWS + k0 + c);
  }
#pragma unroll
  for (int j = 0; j < 8; ++j) {
    int slot = tid + 256 * j;
    int r = slot >> 5, c = (slot & 31) << 3;
    *(short8*)&Bs[0][r][c] = st[j];
  }
  __syncthreads();

  for (int t = 0; t < NST; ++t) {
    int cur = t & 1;
    if (t + 1 < NST) {              // issue next-stage B loads early
      int ks = k0 + (t + 1) * BK;
#pragma unroll
      for (int j = 0; j < 8; ++j) {
        int slot = tid + 256 * j;
        int r = slot >> 5, c = (slot & 31) << 3;
        st[j] = *(const short8*)(BT + (size_t)r * NROWS + ks + c);
      }
    }
    int ks = k0 + t * BK;
#pragma unroll
    for (int k = 0; k < BK; k += 64) {
      short8 a[2][2], b[2][4];
#pragma unroll
      for (int u = 0; u < 2; ++u) {
        int kk = k + u * 32 + kg * 8;
        a[u][0] = *(const short8*)(A0 + ks + kk);
        a[u][1] = *(const short8*)(A1 + ks + kk);
        b[u][0] = *(const short8*)&Bs[cur][l15 +  0][kk];
        b[u][1] = *(const short8*)&Bs[cur][l15 + 16][kk];
        b[u][2] = *(const short8*)&Bs[cur][l15 + 32][kk];
        b[u][3] = *(const short8*)&Bs[cur][l15 + 48][kk];
      }
#pragma unroll
      for (int u = 0; u < 2; ++u)
#pragma unroll
        for (int ct = 0; ct < 4; ++ct) {
          acc[0][ct] = __builtin_amdgcn_mfma_f32_16x16x32_bf16(a[u][0], b[u][ct], acc[0][ct], 0, 0, 0);
          acc[1][ct] = __builtin_amdgcn_mfma_f32_16x16x32_bf16(a[u][1], b[u][ct], acc[1][ct], 0, 0, 0);
        }
    }
    __syncthreads();                 // all waves done reading buf[cur]
    if (t + 1 < NST) {
#pragma unroll
      for (int j = 0; j < 8; ++j) {
        int slot = tid + 256 * j;
        int r = slot >> 5, c = (slot & 31) << 3;
        *(short8*)&Bs[cur ^ 1][r][c] = st[j];
      }
      __syncthreads();               // buf[nxt] visible
    }
  }

  float* Pb = P + (size_t)blockIdx.y * (NROWS * 64);
#pragma unroll
  for (int rt = 0; rt < 2; ++rt)
#pragma unroll
    for (int r = 0; r < 4; ++r) {
      size_t base = (size_t)(wrow + rt * 16 + kg * 4 + r) * 64 + l15;
#pragma unroll
      for (int ct = 0; ct < 4; ++ct) Pb[base + 16 * ct] = acc[rt][ct][r];
    }
}

// P[y][8192][64] = A(fp32, cvt in-loop) @ BT^T (fc1 only). grid (128, SK).
__global__ __launch_bounds__(256, 2) void gemm_a32_u2(
    const float* __restrict__ A, const short* __restrict__ BT,
    float* __restrict__ P, int K, int splitk) {
  int w = threadIdx.x >> 6;
  int l = threadIdx.x & 63;
  int l15 = l & 15, kg = l >> 4;
  int m_base = blockIdx.x * 64 + w * 16;
  const float* Arow = A + (size_t)(m_base + l15) * K;
  const short* Br = BT + (size_t)l15 * K;
  int kchunk = K / splitk;
  int k0 = blockIdx.y * kchunk;
  f32x4 acc[4] = {{0,0,0,0},{0,0,0,0},{0,0,0,0},{0,0,0,0}};
  for (int k = k0; k < k0 + kchunk; k += 64) {
    f32x4 a32[2][2];
    short8 b[2][4];
#pragma unroll
    for (int u = 0; u < 2; ++u) {
      int kk = k + u * 32 + kg * 8;
      a32[u][0] = __builtin_nontemporal_load((const f32x4*)(Arow + kk));
      a32[u][1] = __builtin_nontemporal_load((const f32x4*)(Arow + kk + 4));
      b[u][0] = *(const short8*)(Br + kk);
      b[u][1] = *(const short8*)(Br + (size_t)16 * K + kk);
      b[u][2] = *(const short8*)(Br + (size_t)32 * K + kk);
      b[u][3] = *(const short8*)(Br + (size_t)48 * K + kk);
    }
#pragma unroll
    for (int u = 0; u < 2; ++u) {
      short8 af;
      af[0] = f2bf(a32[u][0].x); af[1] = f2bf(a32[u][0].y);
      af[2] = f2bf(a32[u][0].z); af[3] = f2bf(a32[u][0].w);
      af[4] = f2bf(a32[u][1].x); af[5] = f2bf(a32[u][1].y);
      af[6] = f2bf(a32[u][1].z); af[7] = f2bf(a32[u][1].w);
#pragma unroll
      for (int t = 0; t < 4; ++t)
        acc[t] = __builtin_amdgcn_mfma_f32_16x16x32_bf16(af, b[u][t], acc[t], 0, 0, 0);
    }
  }
  float* Pb = P + (size_t)blockIdx.y * (NROWS * 64);
  int mr = m_base + kg * 4;
#pragma unroll
  for (int r = 0; r < 4; ++r) {
    size_t base = (size_t)(mr + r) * 64 + l15;
#pragma unroll
    for (int t = 0; t < 4; ++t) Pb[base + 16 * t] = acc[t][r];
  }
}

// sum split-K partials + bias (+ residual, relu); float4 per thread.
__global__ __launch_bounds__(256) void reduce4_kernel(
    const float* __restrict__ P, const float* __restrict__ bias,
    const float* __restrict__ Hres, float* __restrict__ Hout,
    float* __restrict__ Out, int mode, int splitk) {
  int gid = blockIdx.x * 256 + threadIdx.x;   // over 8192*16 groups of 4
  int e0 = gid * 4;
  int n = e0 & 63;
  f32x4 s = {0, 0, 0, 0};
  for (int sidx = 0; sidx < splitk; ++sidx)
    s += *(const f32x4*)(P + (size_t)sidx * (NROWS * 64) + e0);
  s += *(const f32x4*)(bias + n);
  if (mode == 0) {
    *(f32x4*)(Hout + e0) = s;
  } else if (mode == 1) {
    s += *(const f32x4*)(Hres + e0);
    s.x = s.x > 0.f ? s.x : 0.f; s.y = s.y > 0.f ? s.y : 0.f;
    s.z = s.z > 0.f ? s.z : 0.f; s.w = s.w > 0.f ? s.w : 0.f;
    *(f32x4*)(Hout + e0) = s;
  } else {
    if (n < 40) {
      int m = e0 >> 6;
      s.x = s.x > 0.f ? s.x : 0.f; s.y = s.y > 0.f ? s.y : 0.f;
      s.z = s.z > 0.f ? s.z : 0.f; s.w = s.w > 0.f ? s.w : 0.f;
      *(f32x4*)(Out + (size_t)m * 40 + n) = s;
    }
  }
}

extern "C" void kernel_launch(void* const* d_in, const int* in_sizes, int n_in,
                              void* d_out, int out_size, void* d_ws, size_t ws_size,
                              hipStream_t stream) {
  const float* x     = (const float*)d_in[0];
  const float* adj1  = (const float*)d_in[1];
  const float* fc1_W = (const float*)d_in[3];
  const float* fc1_b = (const float*)d_in[4];
  const float* W_h   = (const float*)d_in[5];
  const float* b_h   = (const float*)d_in[6];
  const float* W_out = (const float*)d_in[7];
  const float* b_out = (const float*)d_in[8];
  float* out = (float*)d_out;

  char* ws = (char*)d_ws;
  size_t off = 0;
  float* P   = (float*)(ws + off); off += (size_t)SK * NROWS * 64 * 4;   // 16 MiB
  float* h_a = (float*)(ws + off); off += (size_t)NROWS * 64 * 4;
  float* h_b = (float*)(ws + off); off += (size_t)NROWS * 64 * 4;
  short* tT  = (short*)(ws + off); off += (size_t)64 * NROWS * 2;
  short* WT  = (short*)(ws + off); off += (size_t)64 * 1024 * 2;
  size_t adjb_bytes = (size_t)NROWS * NROWS * 2;                         // 128 MiB
  short* AB  = (ws_size - off >= adjb_bytes) ? (short*)(ws + off) : nullptr;

  const int RED_GRID = NROWS * 64 / 4 / 256;

  if (AB)
    convert_adj_kernel<<<2048, 256, 0, stream>>>(adj1, AB);

  // fc1: h = x @ fc1_W + b
  convert_w_kernel<<<(1024 * 64 + 255) / 256, 256, 0, stream>>>(fc1_W, WT, 1024, 64);
  gemm_a32_u2<<<dim3(NROWS / 64, SK), 256, 0, stream>>>(x, WT, P, 1024, SK);
  reduce4_kernel<<<RED_GRID, 256, 0, stream>>>(P, fc1_b, nullptr, h_a, nullptr, 0, SK);

  float* hc = h_a; float* hn = h_b;
  for (int i = 0; i < 3; ++i) {
    small_t_kernel<<<NROWS * 4 / 256, 256, 0, stream>>>(hc, W_h + (size_t)i * 64 * 64, tT, 64, 64);
    if (AB)
      gemm_bf16_lds2<<<dim3(NROWS / MTILE, SK), 256, 0, stream>>>(AB, tT, P);
    else
      gemm_a32_u2<<<dim3(NROWS / 64, SK), 256, 0, stream>>>(adj1, tT, P, NROWS, SK);
    reduce4_kernel<<<RED_GRID, 256, 0, stream>>>(P, b_h + (size_t)i * 64, hc, hn, nullptr, 1, SK);
    float* t = hc; hc = hn; hn = t;
  }

  small_t_kernel<<<NROWS * 4 / 256, 256, 0, stream>>>(hc, W_out, tT, 40, 40);
  if (AB)
    gemm_bf16_lds2<<<dim3(NROWS / MTILE, SK), 256, 0, stream>>>(AB, tT, P);
  else
    gemm_a32_u2<<<dim3(NROWS / 64, SK), 256, 0, stream>>>(adj1, tT, P, NROWS, SK);
  reduce4_kernel<<<RED_GRID, 256, 0, stream>>>(P, b_out, nullptr, nullptr, out, 2, SK);
}